// Round 13
// baseline (223.241 us; speedup 1.0000x reference)
//
#include <hip/hip_runtime.h>
#include <hip/hip_bf16.h>
#include <math.h>

#define BB 1024     // batch
#define LL 50       // sequence length
#define DD 256      // embedding dim
#define TWO_D 512
#define NN 40000    // nodes
#define DEG 12      // neighbors per node (adj_rows = repeat(arange(N), DEG))
#define NITER 50    // entmax bisect iterations

typedef __attribute__((ext_vector_type(8))) short short8;
typedef __attribute__((ext_vector_type(4))) float floatx4;

__device__ __forceinline__ float wave_sum64(float v) {
#pragma unroll
    for (int off = 32; off > 0; off >>= 1) v += __shfl_xor(v, off, 64);
    return v;
}
__device__ __forceinline__ float wave_max64(float v) {
#pragma unroll
    for (int off = 32; off > 0; off >>= 1) v = fmaxf(v, __shfl_xor(v, off, 64));
    return v;
}
__device__ __forceinline__ float bf2f(ushort u) {
    union { unsigned int i; float f; } c; c.i = ((unsigned int)u) << 16; return c.f;
}
__device__ __forceinline__ ushort f2bf(float f) {
    __hip_bfloat16 h = __float2bfloat16(f);
    return *(ushort*)&h;
}
__device__ __forceinline__ float hw_exp2(float x) { return __builtin_amdgcn_exp2f(x); }
__device__ __forceinline__ float hw_log2(float x) { return __builtin_amdgcn_logf(x); }

// ---------------- L1: emb->bf16 | mark | wprep (+w1t fold) ------------------
// bid [0,10000):    ebf = bf16(item_emb)
// bid [10000,10200): flags[items[i]] = 1  (no zero-init needed: !=1 only
//                    causes extra conv work, never wrong values)
// bid [10200,10712): k = bid-10200:
//    Wc[k][n] = sum_d wf_w[d][k]*at_w2[d][n];  v[k] = sum_d wf_w[d][k]*aw[d]
//    k<64  also: w1t[t][4k+j] = bf16(at_w1[4k+j][t])  (proven R11 pattern)
//    k==0  also: bc[n] = sum_d wf_b[d]*at_w2[d][n] + at_bias[n]; c0 = wf_b.aw+ab
__global__ __launch_bounds__(256) void k_stage1(
    const float* __restrict__ emb, ushort* __restrict__ ebf,
    const int* __restrict__ items, int* __restrict__ flags,
    const float* __restrict__ wf_w, const float* __restrict__ wf_b,
    const float* __restrict__ at_w2, const float* __restrict__ at_bias,
    const float* __restrict__ aw, const float* __restrict__ ab,
    const float* __restrict__ at_w1,
    float* __restrict__ Wc, float* __restrict__ v,
    float* __restrict__ bc, float* __restrict__ c0,
    ushort* __restrict__ w1t)
{
    __shared__ float wred[4];
    __shared__ ushort s_t[4][DD];
    int bid = blockIdx.x;
    int tid = threadIdx.x;

    if (bid < 10000) {
        int i = (bid * 256 + tid) * 4;
        float4 val = *(const float4*)(emb + i);
        ushort4 o;
        o.x = f2bf(val.x); o.y = f2bf(val.y); o.z = f2bf(val.z); o.w = f2bf(val.w);
        *(ushort4*)(ebf + i) = o;
    } else if (bid < 10200) {
        int i = (bid - 10000) * 256 + tid;
        flags[items[i]] = 1;
    } else {
        int k = bid - 10200;
        int lane = tid & 63, wv = tid >> 6;

        float acc = 0.f;
#pragma unroll 4
        for (int d = 0; d < DD; ++d)
            acc += wf_w[d * TWO_D + k] * at_w2[d * DD + tid];
        Wc[k * DD + tid] = acc;

        float s1 = wf_w[tid * TWO_D + k] * aw[tid];
        s1 = wave_sum64(s1);
        if (lane == 0) wred[wv] = s1;
        __syncthreads();
        if (tid == 0) v[k] = wred[0] + wred[1] + wred[2] + wred[3];

        if (k < 64) {
            // transpose 4 columns of at_w1: w1t[t][k0+j] = at_w1[k0+j][t]
            int k0 = k * 4;
#pragma unroll
            for (int j = 0; j < 4; ++j)
                s_t[j][tid] = f2bf(at_w1[(k0 + j) * DD + tid]);
            __syncthreads();
            ushort4 pk;
            pk.x = s_t[0][tid]; pk.y = s_t[1][tid];
            pk.z = s_t[2][tid]; pk.w = s_t[3][tid];
            *(ushort4*)(w1t + tid * DD + k0) = pk;
        }

        if (k == 0) {
            float acc2 = at_bias[tid];
#pragma unroll 4
            for (int d = 0; d < DD; ++d)
                acc2 += wf_b[d] * at_w2[d * DD + tid];
            bc[tid] = acc2;
            __syncthreads();
            float s2 = wf_b[tid] * aw[tid];
            s2 = wave_sum64(s2);
            if (lane == 0) wred[wv] = s2;
            __syncthreads();
            if (tid == 0) c0[0] = wred[0] + wred[1] + wred[2] + wred[3] + ab[0];
        }
    }
}

// ---------------- L2: conv_dedup | t2 direct + alpha ------------------------
// bid [0,10000): per-node conv (one wave per node, skip unflagged)
// bid [10000,11024): t2[b,n] = tgt[b,:]@Wc[:,n] + bc[n]; ntile==0 emits alpha
__global__ __launch_bounds__(256) void k_stage2(
    const ushort* __restrict__ ebf, const int* __restrict__ adj_cols,
    const float* __restrict__ adj_vals, const int* __restrict__ flags,
    ushort* __restrict__ gbf,
    const float* __restrict__ tgt, const float* __restrict__ Wc,
    const float* __restrict__ bc, const float* __restrict__ v,
    const float* __restrict__ c0, float* __restrict__ t2,
    float* __restrict__ alpha)
{
    __shared__ float x_s[4 * TWO_D];
    int bid = blockIdx.x;
    int tid = threadIdx.x;
    int wv = tid >> 6, lane = tid & 63;

    if (bid < 10000) {
        int n = bid * 4 + wv;
        if (flags[n] != 1) return;
        int colv = 0; float valv = 0.f;
        if (lane < DEG) { colv = adj_cols[n * DEG + lane]; valv = adj_vals[n * DEG + lane]; }
        int cols[DEG]; float vals[DEG];
#pragma unroll
        for (int k = 0; k < DEG; ++k) {
            cols[k] = __shfl(colv, k, 64);
            vals[k] = __shfl(valv, k, 64);
        }
        ushort4 s = *(const ushort4*)(ebf + (size_t)n * DD + lane * 4);
        ushort4 e[DEG];
#pragma unroll
        for (int k = 0; k < DEG; ++k)
            e[k] = *(const ushort4*)(ebf + (size_t)cols[k] * DD + lane * 4);
        float a0 = bf2f(s.x), a1 = bf2f(s.y), a2 = bf2f(s.z), a3 = bf2f(s.w);
#pragma unroll
        for (int k = 0; k < DEG; ++k) {
            float vv = vals[k];
            a0 += vv * bf2f(e[k].x); a1 += vv * bf2f(e[k].y);
            a2 += vv * bf2f(e[k].z); a3 += vv * bf2f(e[k].w);
        }
        ushort4 o;
        o.x = f2bf(0.5f * a0); o.y = f2bf(0.5f * a1);
        o.z = f2bf(0.5f * a2); o.w = f2bf(0.5f * a3);
        *(ushort4*)(gbf + (size_t)n * DD + lane * 4) = o;
    } else {
        int t = bid - 10000;
        int btile = t >> 2, ntile = t & 3;
        int b0 = btile * 4, n0 = ntile * 64;
        int j = wv;
        for (int i = tid; i < 4 * TWO_D; i += 256) x_s[i] = tgt[b0 * TWO_D + i];
        __syncthreads();

        float acc = bc[n0 + lane];
        const float* xr = x_s + j * TWO_D;
#pragma unroll 8
        for (int k = 0; k < TWO_D; ++k)
            acc += xr[k] * Wc[k * DD + n0 + lane];
        t2[(b0 + j) * DD + n0 + lane] = acc;

        if (ntile == 0) {
            float s = 0.f;
#pragma unroll
            for (int i = 0; i < 8; ++i) s += xr[lane + 64 * i] * v[lane + 64 * i];
            s = wave_sum64(s);
            if (lane == 0) {
                float a = 1.f + 1.f / (1.f + expf(-(s + c0[0])));
                if (a == 1.f) a = 1.00001f;
                alpha[b0 + j] = a;
            }
        }
    }
}

// ---------------- L3 (MFMA, 128-row tile) -----------------------------------
__global__ __launch_bounds__(256, 2) void k_scores_mfma(
    const int* __restrict__ items, const ushort* __restrict__ gbf,
    const ushort* __restrict__ w1t, const float* __restrict__ t2,
    const float* __restrict__ at_w0, float* __restrict__ scores)
{
    __shared__ __align__(16) ushort sA[128 * 72];   // 18432 B
    __shared__ __align__(16) ushort sB[256 * 72];   // 36864 B
    __shared__ float sred[128][4];
    __shared__ int s_items[128];
    int tid = threadIdx.x;
    int blk = blockIdx.x;
    int lane = tid & 63, wv = tid >> 6;
    int cn = lane & 15, q = lane >> 4;
    int n0 = wv * 64;

    if (tid < 128) s_items[tid] = items[blk * 128 + tid];
    __syncthreads();

    floatx4 acc[8][4];
#pragma unroll
    for (int mt = 0; mt < 8; ++mt)
#pragma unroll
        for (int nt = 0; nt < 4; ++nt)
            acc[mt][nt] = (floatx4){0.f, 0.f, 0.f, 0.f};

#pragma unroll 1
    for (int kc = 0; kc < 4; ++kc) {
#pragma unroll
        for (int it = 0; it < 4; ++it) {
            int i = tid + it * 256;
            int row = i >> 3, seg = i & 7;
            *(uint4*)(sA + row * 72 + seg * 8) =
                *(const uint4*)(gbf + (size_t)s_items[row] * DD + kc * 64 + seg * 8);
        }
#pragma unroll
        for (int it = 0; it < 8; ++it) {
            int i = tid + it * 256;
            int n = i >> 3, seg = i & 7;
            *(uint4*)(sB + n * 72 + seg * 8) =
                *(const uint4*)(w1t + n * DD + kc * 64 + seg * 8);
        }
        __syncthreads();
#pragma unroll
        for (int ks = 0; ks < 2; ++ks) {
            short8 af[8], bfr[4];
#pragma unroll
            for (int mt = 0; mt < 8; ++mt)
                af[mt] = *(const short8*)(sA + (mt * 16 + cn) * 72 + ks * 32 + q * 8);
#pragma unroll
            for (int nt = 0; nt < 4; ++nt)
                bfr[nt] = *(const short8*)(sB + (n0 + nt * 16 + cn) * 72 + ks * 32 + q * 8);
#pragma unroll
            for (int mt = 0; mt < 8; ++mt)
#pragma unroll
                for (int nt = 0; nt < 4; ++nt)
                    acc[mt][nt] = __builtin_amdgcn_mfma_f32_16x16x32_bf16(
                        af[mt], bfr[nt], acc[mt][nt], 0, 0, 0);
        }
        __syncthreads();
    }

    float w0v[4];
#pragma unroll
    for (int nt = 0; nt < 4; ++nt) w0v[nt] = at_w0[n0 + nt * 16 + cn];
#pragma unroll
    for (int mt = 0; mt < 8; ++mt) {
#pragma unroll
        for (int r = 0; r < 4; ++r) {
            int row_in = q * 4 + r;
            int row = mt * 16 + row_in;
            int b = (blk * 128 + row) / LL;
            const float* t2b = t2 + b * DD;
            float p = 0.f;
#pragma unroll
            for (int nt = 0; nt < 4; ++nt) {
                int col = n0 + nt * 16 + cn;
                float vv = acc[mt][nt][r] + t2b[col];
                p += fmaxf(vv, 0.f) * w0v[nt];
            }
            p += __shfl_xor(p, 1, 64);
            p += __shfl_xor(p, 2, 64);
            p += __shfl_xor(p, 4, 64);
            p += __shfl_xor(p, 8, 64);
            if (cn == 0) sred[row][wv] = p;
        }
    }
    __syncthreads();
    if (tid < 128)
        scores[blk * 128 + tid] = sred[tid][0] + sred[tid][1] + sred[tid][2] + sred[tid][3];
}

__device__ __forceinline__ float pw(float z, float invv) {
    return hw_exp2(invv * hw_log2(z));   // z=0 -> exp2(-inf)=0, correct limit
}

// ---------------- L4: entmax + weighted sum + selu + L2 norm ----------------
__global__ __launch_bounds__(256) void k_entmax_out(
    const float* __restrict__ scores, const float* __restrict__ alpha,
    const int* __restrict__ items, const ushort* __restrict__ gbf,
    float* __restrict__ out)
{
    __shared__ float attn_s[LL];
    __shared__ int s_it[LL];
    __shared__ float red[4];
    int b = blockIdx.x;
    int tid = threadIdx.x;

    if (tid >= 192 && tid < 192 + LL) s_it[tid - 192] = items[b * LL + (tid - 192)];

    if (tid < 64) {
        int l = tid;
        float a = alpha[b];
        float am1 = a - 1.f;
        float invv = 1.f / am1;
        float x = (l < LL) ? scores[b * LL + l] : -__builtin_inff();
        float Xa = x * am1;

        float mx = wave_max64(Xa);
        float tau_lo = mx - 1.f;
        float tau_hi = mx - hw_exp2(am1 * hw_log2(1.f / (float)LL));

        float f_lo = wave_sum64(pw(fmaxf(Xa - tau_lo, 0.f), invv)) - 1.f;

        float dm = tau_hi - tau_lo;
        float tau_m = tau_lo;
#pragma unroll 1
        for (int it = 0; it < NITER; ++it) {
            dm *= 0.5f;
            tau_m = tau_lo + dm;
            // exact early-exit: once dm rounds away, every remaining
            // iteration is a no-op (rounding monotonicity) -> identical result
            if (tau_m == tau_lo) break;
            float f_m = wave_sum64(pw(fmaxf(Xa - tau_m, 0.f), invv)) - 1.f;
            if (f_m * f_lo >= 0.f) tau_lo = tau_m;
        }
        float pm = pw(fmaxf(Xa - tau_m, 0.f), invv);
        float s = wave_sum64(pm);
        if (l < LL) attn_s[l] = pm / s;
    }
    __syncthreads();

    int d = tid;
    float c = 0.f;
#pragma unroll
    for (int l = 0; l < LL; ++l)
        c += attn_s[l] * bf2f(gbf[(size_t)s_it[l] * DD + d]);

    const float SC = 1.0507009873554805f;
    const float AL = 1.6732632423543772f;
    c = SC * (c > 0.f ? c : AL * expm1f(c));

    float ss = wave_sum64(c * c);
    int wv = tid >> 6, lane = tid & 63;
    if (lane == 0) red[wv] = ss;
    __syncthreads();
    float tot = red[0] + red[1] + red[2] + red[3];
    out[b * DD + d] = c / sqrtf(tot);
}

extern "C" void kernel_launch(void* const* d_in, const int* in_sizes, int n_in,
                              void* d_out, int out_size, void* d_ws, size_t ws_size,
                              hipStream_t stream) {
    const int*   items     = (const int*)  d_in[0];
    const float* tgt       = (const float*)d_in[3];
    const float* item_emb  = (const float*)d_in[4];
    const int*   adj_cols  = (const int*)  d_in[6];
    const float* adj_vals  = (const float*)d_in[7];
    const float* wf_w      = (const float*)d_in[8];
    const float* wf_b      = (const float*)d_in[9];
    const float* alphaw_w  = (const float*)d_in[10];
    const float* alphaw_b  = (const float*)d_in[11];
    const float* at_w0     = (const float*)d_in[12];
    const float* at_w1     = (const float*)d_in[13];
    const float* at_w2     = (const float*)d_in[14];
    const float* at_bias   = (const float*)d_in[15];

    const size_t SZ_TAB = (size_t)NN * DD * sizeof(ushort);      // 20.48 MB
    char* ws = (char*)d_ws;
    ushort* gbf = (ushort*)ws;   ws += SZ_TAB;
    ushort* ebf = (ushort*)ws;   ws += SZ_TAB;
    ushort* w1t = (ushort*)ws;   ws += (size_t)DD * DD * sizeof(ushort);
    int*   flags = (int*)ws;     ws += (size_t)NN * sizeof(int);
    float* Wc     = (float*)ws;  ws += (size_t)TWO_D * DD * sizeof(float);
    float* bcv    = (float*)ws;  ws += (size_t)DD * sizeof(float);
    float* vv     = (float*)ws;  ws += (size_t)TWO_D * sizeof(float);
    float* c0v    = (float*)ws;  ws += 16 * sizeof(float);
    float* t2     = (float*)ws;  ws += (size_t)BB * DD * sizeof(float);
    float* alpha  = (float*)ws;  ws += ((size_t)BB + 32) * sizeof(float);
    float* scores = (float*)ws;  ws += (size_t)BB * LL * sizeof(float);
    float* out    = (float*)d_out;

    k_stage1<<<10712, 256, 0, stream>>>(item_emb, ebf, items, flags,
                                        wf_w, wf_b, at_w2, at_bias,
                                        alphaw_w, alphaw_b, at_w1,
                                        Wc, vv, bcv, c0v, w1t);
    k_stage2<<<11024, 256, 0, stream>>>(ebf, adj_cols, adj_vals, flags, gbf,
                                        tgt, Wc, bcv, vv, c0v, t2, alpha);
    k_scores_mfma<<<(BB * LL) / 128, 256, 0, stream>>>(items, gbf, w1t, t2, at_w0, scores);
    k_entmax_out<<<BB, 256, 0, stream>>>(scores, alpha, items, gbf, out);
}

// Round 14
// 204.326 us; speedup vs baseline: 1.0926x; 1.0926x over previous
//
#include <hip/hip_runtime.h>
#include <hip/hip_bf16.h>
#include <math.h>

#define BB 1024     // batch
#define LL 50       // sequence length
#define DD 256      // embedding dim
#define TWO_D 512
#define NN 40000    // nodes
#define DEG 12      // neighbors per node (adj_rows = repeat(arange(N), DEG))
#define NITER 50    // entmax bisect iterations

typedef __attribute__((ext_vector_type(8))) short short8;
typedef __attribute__((ext_vector_type(4))) float floatx4;

__device__ __forceinline__ float wave_sum64(float v) {
#pragma unroll
    for (int off = 32; off > 0; off >>= 1) v += __shfl_xor(v, off, 64);
    return v;
}
__device__ __forceinline__ float wave_max64(float v) {
#pragma unroll
    for (int off = 32; off > 0; off >>= 1) v = fmaxf(v, __shfl_xor(v, off, 64));
    return v;
}
__device__ __forceinline__ float bf2f(ushort u) {
    union { unsigned int i; float f; } c; c.i = ((unsigned int)u) << 16; return c.f;
}
__device__ __forceinline__ ushort f2bf(float f) {
    __hip_bfloat16 h = __float2bfloat16(f);
    return *(ushort*)&h;
}
__device__ __forceinline__ float hw_exp2(float x) { return __builtin_amdgcn_exp2f(x); }
__device__ __forceinline__ float hw_log2(float x) { return __builtin_amdgcn_logf(x); }

// ---------------- L1: wprep (+w1t fold) | mark | emb->bf16 ------------------
// Long-pole blocks FIRST so they overlap the 10000 short emb blocks
// (R13 lesson: trailing heterogeneous blocks serialize after the bulk).
// bid [0,512):      k = bid:
//    Wc[k][n] = sum_d wf_w[d][k]*at_w2[d][n];  v[k] = sum_d wf_w[d][k]*aw[d]
//    k<64  also: w1t[t][4k+j] = bf16(at_w1[4k+j][t])
//    k==0  also: bc[n] = sum_d wf_b[d]*at_w2[d][n] + at_bias[n]; c0 = wf_b.aw+ab
// bid [512,712):    flags[items[i]] = 1  (no zero-init needed: !=1 only causes
//                   extra conv work, never wrong values)
// bid [712,10712):  ebf = bf16(item_emb)
__global__ __launch_bounds__(256) void k_stage1(
    const float* __restrict__ emb, ushort* __restrict__ ebf,
    const int* __restrict__ items, int* __restrict__ flags,
    const float* __restrict__ wf_w, const float* __restrict__ wf_b,
    const float* __restrict__ at_w2, const float* __restrict__ at_bias,
    const float* __restrict__ aw, const float* __restrict__ ab,
    const float* __restrict__ at_w1,
    float* __restrict__ Wc, float* __restrict__ v,
    float* __restrict__ bc, float* __restrict__ c0,
    ushort* __restrict__ w1t)
{
    __shared__ float wred[4];
    __shared__ ushort s_t[4][DD];
    int bid = blockIdx.x;
    int tid = threadIdx.x;

    if (bid < 512) {
        int k = bid;
        int lane = tid & 63, wv = tid >> 6;

        float acc = 0.f;
#pragma unroll 4
        for (int d = 0; d < DD; ++d)
            acc += wf_w[d * TWO_D + k] * at_w2[d * DD + tid];
        Wc[k * DD + tid] = acc;

        float s1 = wf_w[tid * TWO_D + k] * aw[tid];
        s1 = wave_sum64(s1);
        if (lane == 0) wred[wv] = s1;
        __syncthreads();
        if (tid == 0) v[k] = wred[0] + wred[1] + wred[2] + wred[3];

        if (k < 64) {
            // transpose 4 columns of at_w1: w1t[t][k0+j] = at_w1[k0+j][t]
            int k0 = k * 4;
#pragma unroll
            for (int j = 0; j < 4; ++j)
                s_t[j][tid] = f2bf(at_w1[(k0 + j) * DD + tid]);
            __syncthreads();
            ushort4 pk;
            pk.x = s_t[0][tid]; pk.y = s_t[1][tid];
            pk.z = s_t[2][tid]; pk.w = s_t[3][tid];
            *(ushort4*)(w1t + tid * DD + k0) = pk;
        }

        if (k == 0) {
            float acc2 = at_bias[tid];
#pragma unroll 4
            for (int d = 0; d < DD; ++d)
                acc2 += wf_b[d] * at_w2[d * DD + tid];
            bc[tid] = acc2;
            __syncthreads();
            float s2 = wf_b[tid] * aw[tid];
            s2 = wave_sum64(s2);
            if (lane == 0) wred[wv] = s2;
            __syncthreads();
            if (tid == 0) c0[0] = wred[0] + wred[1] + wred[2] + wred[3] + ab[0];
        }
    } else if (bid < 712) {
        int i = (bid - 512) * 256 + tid;
        flags[items[i]] = 1;
    } else {
        int i = ((bid - 712) * 256 + tid) * 4;
        float4 val = *(const float4*)(emb + i);
        ushort4 o;
        o.x = f2bf(val.x); o.y = f2bf(val.y); o.z = f2bf(val.z); o.w = f2bf(val.w);
        *(ushort4*)(ebf + i) = o;
    }
}

// ---------------- L2: t2 direct + alpha | conv_dedup ------------------------
// t2a blocks FIRST (1024, long per-block GEMV) so they overlap conv.
// bid [0,1024): t2[b,n] = tgt[b,:]@Wc[:,n] + bc[n]; ntile==0 emits alpha
// bid [1024,11024): per-node conv (one wave per node, skip unflagged)
__global__ __launch_bounds__(256) void k_stage2(
    const ushort* __restrict__ ebf, const int* __restrict__ adj_cols,
    const float* __restrict__ adj_vals, const int* __restrict__ flags,
    ushort* __restrict__ gbf,
    const float* __restrict__ tgt, const float* __restrict__ Wc,
    const float* __restrict__ bc, const float* __restrict__ v,
    const float* __restrict__ c0, float* __restrict__ t2,
    float* __restrict__ alpha)
{
    __shared__ float x_s[4 * TWO_D];
    int bid = blockIdx.x;
    int tid = threadIdx.x;
    int wv = tid >> 6, lane = tid & 63;

    if (bid < 1024) {
        int t = bid;
        int btile = t >> 2, ntile = t & 3;
        int b0 = btile * 4, n0 = ntile * 64;
        int j = wv;
        for (int i = tid; i < 4 * TWO_D; i += 256) x_s[i] = tgt[b0 * TWO_D + i];
        __syncthreads();

        float acc = bc[n0 + lane];
        const float* xr = x_s + j * TWO_D;
#pragma unroll 8
        for (int k = 0; k < TWO_D; ++k)
            acc += xr[k] * Wc[k * DD + n0 + lane];
        t2[(b0 + j) * DD + n0 + lane] = acc;

        if (ntile == 0) {
            float s = 0.f;
#pragma unroll
            for (int i = 0; i < 8; ++i) s += xr[lane + 64 * i] * v[lane + 64 * i];
            s = wave_sum64(s);
            if (lane == 0) {
                float a = 1.f + 1.f / (1.f + expf(-(s + c0[0])));
                if (a == 1.f) a = 1.00001f;
                alpha[b0 + j] = a;
            }
        }
    } else {
        int n = (bid - 1024) * 4 + wv;
        if (flags[n] != 1) return;
        int colv = 0; float valv = 0.f;
        if (lane < DEG) { colv = adj_cols[n * DEG + lane]; valv = adj_vals[n * DEG + lane]; }
        int cols[DEG]; float vals[DEG];
#pragma unroll
        for (int k = 0; k < DEG; ++k) {
            cols[k] = __shfl(colv, k, 64);
            vals[k] = __shfl(valv, k, 64);
        }
        ushort4 s = *(const ushort4*)(ebf + (size_t)n * DD + lane * 4);
        ushort4 e[DEG];
#pragma unroll
        for (int k = 0; k < DEG; ++k)
            e[k] = *(const ushort4*)(ebf + (size_t)cols[k] * DD + lane * 4);
        float a0 = bf2f(s.x), a1 = bf2f(s.y), a2 = bf2f(s.z), a3 = bf2f(s.w);
#pragma unroll
        for (int k = 0; k < DEG; ++k) {
            float vv = vals[k];
            a0 += vv * bf2f(e[k].x); a1 += vv * bf2f(e[k].y);
            a2 += vv * bf2f(e[k].z); a3 += vv * bf2f(e[k].w);
        }
        ushort4 o;
        o.x = f2bf(0.5f * a0); o.y = f2bf(0.5f * a1);
        o.z = f2bf(0.5f * a2); o.w = f2bf(0.5f * a3);
        *(ushort4*)(gbf + (size_t)n * DD + lane * 4) = o;
    }
}

// ---------------- L3 (MFMA, 128-row tile) -----------------------------------
__global__ __launch_bounds__(256, 2) void k_scores_mfma(
    const int* __restrict__ items, const ushort* __restrict__ gbf,
    const ushort* __restrict__ w1t, const float* __restrict__ t2,
    const float* __restrict__ at_w0, float* __restrict__ scores)
{
    __shared__ __align__(16) ushort sA[128 * 72];   // 18432 B
    __shared__ __align__(16) ushort sB[256 * 72];   // 36864 B
    __shared__ float sred[128][4];
    __shared__ int s_items[128];
    int tid = threadIdx.x;
    int blk = blockIdx.x;
    int lane = tid & 63, wv = tid >> 6;
    int cn = lane & 15, q = lane >> 4;
    int n0 = wv * 64;

    if (tid < 128) s_items[tid] = items[blk * 128 + tid];
    __syncthreads();

    floatx4 acc[8][4];
#pragma unroll
    for (int mt = 0; mt < 8; ++mt)
#pragma unroll
        for (int nt = 0; nt < 4; ++nt)
            acc[mt][nt] = (floatx4){0.f, 0.f, 0.f, 0.f};

#pragma unroll 1
    for (int kc = 0; kc < 4; ++kc) {
#pragma unroll
        for (int it = 0; it < 4; ++it) {
            int i = tid + it * 256;
            int row = i >> 3, seg = i & 7;
            *(uint4*)(sA + row * 72 + seg * 8) =
                *(const uint4*)(gbf + (size_t)s_items[row] * DD + kc * 64 + seg * 8);
        }
#pragma unroll
        for (int it = 0; it < 8; ++it) {
            int i = tid + it * 256;
            int n = i >> 3, seg = i & 7;
            *(uint4*)(sB + n * 72 + seg * 8) =
                *(const uint4*)(w1t + n * DD + kc * 64 + seg * 8);
        }
        __syncthreads();
#pragma unroll
        for (int ks = 0; ks < 2; ++ks) {
            short8 af[8], bfr[4];
#pragma unroll
            for (int mt = 0; mt < 8; ++mt)
                af[mt] = *(const short8*)(sA + (mt * 16 + cn) * 72 + ks * 32 + q * 8);
#pragma unroll
            for (int nt = 0; nt < 4; ++nt)
                bfr[nt] = *(const short8*)(sB + (n0 + nt * 16 + cn) * 72 + ks * 32 + q * 8);
#pragma unroll
            for (int mt = 0; mt < 8; ++mt)
#pragma unroll
                for (int nt = 0; nt < 4; ++nt)
                    acc[mt][nt] = __builtin_amdgcn_mfma_f32_16x16x32_bf16(
                        af[mt], bfr[nt], acc[mt][nt], 0, 0, 0);
        }
        __syncthreads();
    }

    float w0v[4];
#pragma unroll
    for (int nt = 0; nt < 4; ++nt) w0v[nt] = at_w0[n0 + nt * 16 + cn];
#pragma unroll
    for (int mt = 0; mt < 8; ++mt) {
#pragma unroll
        for (int r = 0; r < 4; ++r) {
            int row_in = q * 4 + r;
            int row = mt * 16 + row_in;
            int b = (blk * 128 + row) / LL;
            const float* t2b = t2 + b * DD;
            float p = 0.f;
#pragma unroll
            for (int nt = 0; nt < 4; ++nt) {
                int col = n0 + nt * 16 + cn;
                float vv = acc[mt][nt][r] + t2b[col];
                p += fmaxf(vv, 0.f) * w0v[nt];
            }
            p += __shfl_xor(p, 1, 64);
            p += __shfl_xor(p, 2, 64);
            p += __shfl_xor(p, 4, 64);
            p += __shfl_xor(p, 8, 64);
            if (cn == 0) sred[row][wv] = p;
        }
    }
    __syncthreads();
    if (tid < 128)
        scores[blk * 128 + tid] = sred[tid][0] + sred[tid][1] + sred[tid][2] + sred[tid][3];
}

__device__ __forceinline__ float pw(float z, float invv) {
    return hw_exp2(invv * hw_log2(z));   // z=0 -> exp2(-inf)=0, correct limit
}

// ---------------- L4: entmax + weighted sum + selu + L2 norm ----------------
__global__ __launch_bounds__(256) void k_entmax_out(
    const float* __restrict__ scores, const float* __restrict__ alpha,
    const int* __restrict__ items, const ushort* __restrict__ gbf,
    float* __restrict__ out)
{
    __shared__ float attn_s[LL];
    __shared__ int s_it[LL];
    __shared__ float red[4];
    int b = blockIdx.x;
    int tid = threadIdx.x;

    if (tid >= 192 && tid < 192 + LL) s_it[tid - 192] = items[b * LL + (tid - 192)];

    if (tid < 64) {
        int l = tid;
        float a = alpha[b];
        float am1 = a - 1.f;
        float invv = 1.f / am1;
        float x = (l < LL) ? scores[b * LL + l] : -__builtin_inff();
        float Xa = x * am1;

        float mx = wave_max64(Xa);
        float tau_lo = mx - 1.f;
        float tau_hi = mx - hw_exp2(am1 * hw_log2(1.f / (float)LL));

        float f_lo = wave_sum64(pw(fmaxf(Xa - tau_lo, 0.f), invv)) - 1.f;

        float dm = tau_hi - tau_lo;
        float tau_m = tau_lo;
#pragma unroll 1
        for (int it = 0; it < NITER; ++it) {
            dm *= 0.5f;
            tau_m = tau_lo + dm;
            // exact early-exit: once dm rounds away, every remaining
            // iteration is a no-op (rounding monotonicity) -> identical result
            if (tau_m == tau_lo) break;
            float f_m = wave_sum64(pw(fmaxf(Xa - tau_m, 0.f), invv)) - 1.f;
            if (f_m * f_lo >= 0.f) tau_lo = tau_m;
        }
        float pm = pw(fmaxf(Xa - tau_m, 0.f), invv);
        float s = wave_sum64(pm);
        if (l < LL) attn_s[l] = pm / s;
    }
    __syncthreads();

    int d = tid;
    float c = 0.f;
#pragma unroll
    for (int l = 0; l < LL; ++l)
        c += attn_s[l] * bf2f(gbf[(size_t)s_it[l] * DD + d]);

    const float SC = 1.0507009873554805f;
    const float AL = 1.6732632423543772f;
    c = SC * (c > 0.f ? c : AL * expm1f(c));

    float ss = wave_sum64(c * c);
    int wv = tid >> 6, lane = tid & 63;
    if (lane == 0) red[wv] = ss;
    __syncthreads();
    float tot = red[0] + red[1] + red[2] + red[3];
    out[b * DD + d] = c / sqrtf(tot);
}

extern "C" void kernel_launch(void* const* d_in, const int* in_sizes, int n_in,
                              void* d_out, int out_size, void* d_ws, size_t ws_size,
                              hipStream_t stream) {
    const int*   items     = (const int*)  d_in[0];
    const float* tgt       = (const float*)d_in[3];
    const float* item_emb  = (const float*)d_in[4];
    const int*   adj_cols  = (const int*)  d_in[6];
    const float* adj_vals  = (const float*)d_in[7];
    const float* wf_w      = (const float*)d_in[8];
    const float* wf_b      = (const float*)d_in[9];
    const float* alphaw_w  = (const float*)d_in[10];
    const float* alphaw_b  = (const float*)d_in[11];
    const float* at_w0     = (const float*)d_in[12];
    const float* at_w1     = (const float*)d_in[13];
    const float* at_w2     = (const float*)d_in[14];
    const float* at_bias   = (const float*)d_in[15];

    const size_t SZ_TAB = (size_t)NN * DD * sizeof(ushort);      // 20.48 MB
    char* ws = (char*)d_ws;
    ushort* gbf = (ushort*)ws;   ws += SZ_TAB;
    ushort* ebf = (ushort*)ws;   ws += SZ_TAB;
    ushort* w1t = (ushort*)ws;   ws += (size_t)DD * DD * sizeof(ushort);
    int*   flags = (int*)ws;     ws += (size_t)NN * sizeof(int);
    float* Wc     = (float*)ws;  ws += (size_t)TWO_D * DD * sizeof(float);
    float* bcv    = (float*)ws;  ws += (size_t)DD * sizeof(float);
    float* vv     = (float*)ws;  ws += (size_t)TWO_D * sizeof(float);
    float* c0v    = (float*)ws;  ws += 16 * sizeof(float);
    float* t2     = (float*)ws;  ws += (size_t)BB * DD * sizeof(float);
    float* alpha  = (float*)ws;  ws += ((size_t)BB + 32) * sizeof(float);
    float* scores = (float*)ws;  ws += (size_t)BB * LL * sizeof(float);
    float* out    = (float*)d_out;

    k_stage1<<<10712, 256, 0, stream>>>(item_emb, ebf, items, flags,
                                        wf_w, wf_b, at_w2, at_bias,
                                        alphaw_w, alphaw_b, at_w1,
                                        Wc, vv, bcv, c0v, w1t);
    k_stage2<<<11024, 256, 0, stream>>>(ebf, adj_cols, adj_vals, flags, gbf,
                                        tgt, Wc, bcv, vv, c0v, t2, alpha);
    k_scores_mfma<<<(BB * LL) / 128, 256, 0, stream>>>(items, gbf, w1t, t2, at_w0, scores);
    k_entmax_out<<<BB, 256, 0, stream>>>(scores, alpha, items, gbf, out);
}

// Round 15
// 198.775 us; speedup vs baseline: 1.1231x; 1.0279x over previous
//
#include <hip/hip_runtime.h>
#include <hip/hip_bf16.h>
#include <math.h>

#define BB 1024     // batch
#define LL 50       // sequence length
#define DD 256      // embedding dim
#define TWO_D 512
#define NN 40000    // nodes
#define DEG 12      // neighbors per node (adj_rows = repeat(arange(N), DEG))
#define NITER 50    // entmax bisect iterations

typedef __attribute__((ext_vector_type(8))) short short8;
typedef __attribute__((ext_vector_type(4))) float floatx4;

__device__ __forceinline__ float wave_sum64(float v) {
#pragma unroll
    for (int off = 32; off > 0; off >>= 1) v += __shfl_xor(v, off, 64);
    return v;
}
__device__ __forceinline__ float wave_max64(float v) {
#pragma unroll
    for (int off = 32; off > 0; off >>= 1) v = fmaxf(v, __shfl_xor(v, off, 64));
    return v;
}
__device__ __forceinline__ float bf2f(ushort u) {
    union { unsigned int i; float f; } c; c.i = ((unsigned int)u) << 16; return c.f;
}
__device__ __forceinline__ ushort f2bf(float f) {
    __hip_bfloat16 h = __float2bfloat16(f);
    return *(ushort*)&h;
}
__device__ __forceinline__ float hw_exp2(float x) { return __builtin_amdgcn_exp2f(x); }
__device__ __forceinline__ float hw_log2(float x) { return __builtin_amdgcn_logf(x); }

// ---------------- L1: wprep (+w1t fold) | mark | emb->bf16 ------------------
// Long-pole blocks FIRST (R13 lesson). Emb convert uses 8 independent float4
// loads per thread for MLP (R14 lesson: 1 load/thread blocks on latency).
// bid [0,512):     k = bid: Wc[k][:], v[k]; k<64: w1t cols; k==0: bc, c0
// bid [512,712):   flags[items[i]] = 1  (no zero-init needed: !=1 only causes
//                  extra conv work, never wrong values)
// bid [712,1962):  ebf = bf16(item_emb), 8 float4 per thread
__global__ __launch_bounds__(256) void k_stage1(
    const float* __restrict__ emb, ushort* __restrict__ ebf,
    const int* __restrict__ items, int* __restrict__ flags,
    const float* __restrict__ wf_w, const float* __restrict__ wf_b,
    const float* __restrict__ at_w2, const float* __restrict__ at_bias,
    const float* __restrict__ aw, const float* __restrict__ ab,
    const float* __restrict__ at_w1,
    float* __restrict__ Wc, float* __restrict__ v,
    float* __restrict__ bc, float* __restrict__ c0,
    ushort* __restrict__ w1t)
{
    __shared__ float wred[4];
    __shared__ ushort s_t[4][DD];
    int bid = blockIdx.x;
    int tid = threadIdx.x;

    if (bid < 512) {
        int k = bid;
        int lane = tid & 63, wv = tid >> 6;

        // 4 independent accumulators -> 4 loads in flight, no serial FMA chain
        float a0 = 0.f, a1 = 0.f, a2 = 0.f, a3 = 0.f;
#pragma unroll 8
        for (int d = 0; d < DD; d += 4) {
            a0 += wf_w[(d + 0) * TWO_D + k] * at_w2[(d + 0) * DD + tid];
            a1 += wf_w[(d + 1) * TWO_D + k] * at_w2[(d + 1) * DD + tid];
            a2 += wf_w[(d + 2) * TWO_D + k] * at_w2[(d + 2) * DD + tid];
            a3 += wf_w[(d + 3) * TWO_D + k] * at_w2[(d + 3) * DD + tid];
        }
        Wc[k * DD + tid] = (a0 + a1) + (a2 + a3);

        float s1 = wf_w[tid * TWO_D + k] * aw[tid];
        s1 = wave_sum64(s1);
        if (lane == 0) wred[wv] = s1;
        __syncthreads();
        if (tid == 0) v[k] = wred[0] + wred[1] + wred[2] + wred[3];

        if (k < 64) {
            // transpose 4 columns of at_w1: w1t[t][k0+j] = at_w1[k0+j][t]
            int k0 = k * 4;
#pragma unroll
            for (int j = 0; j < 4; ++j)
                s_t[j][tid] = f2bf(at_w1[(k0 + j) * DD + tid]);
            __syncthreads();
            ushort4 pk;
            pk.x = s_t[0][tid]; pk.y = s_t[1][tid];
            pk.z = s_t[2][tid]; pk.w = s_t[3][tid];
            *(ushort4*)(w1t + tid * DD + k0) = pk;
        }

        if (k == 0) {
            float b0 = 0.f, b1 = 0.f, b2 = 0.f, b3 = 0.f;
#pragma unroll 8
            for (int d = 0; d < DD; d += 4) {
                b0 += wf_b[d + 0] * at_w2[(d + 0) * DD + tid];
                b1 += wf_b[d + 1] * at_w2[(d + 1) * DD + tid];
                b2 += wf_b[d + 2] * at_w2[(d + 2) * DD + tid];
                b3 += wf_b[d + 3] * at_w2[(d + 3) * DD + tid];
            }
            bc[tid] = at_bias[tid] + (b0 + b1) + (b2 + b3);
            __syncthreads();
            float s2 = wf_b[tid] * aw[tid];
            s2 = wave_sum64(s2);
            if (lane == 0) wred[wv] = s2;
            __syncthreads();
            if (tid == 0) c0[0] = wred[0] + wred[1] + wred[2] + wred[3] + ab[0];
        }
    } else if (bid < 712) {
        int i = (bid - 512) * 256 + tid;
        flags[items[i]] = 1;
    } else {
        // 8 independent float4 loads per thread (MLP), coalesced per step
        int base4 = (bid - 712) * (256 * 8) + tid;   // float4 index
        float4 val[8];
#pragma unroll
        for (int j = 0; j < 8; ++j)
            val[j] = *(const float4*)(emb + (size_t)(base4 + j * 256) * 4);
#pragma unroll
        for (int j = 0; j < 8; ++j) {
            ushort4 o;
            o.x = f2bf(val[j].x); o.y = f2bf(val[j].y);
            o.z = f2bf(val[j].z); o.w = f2bf(val[j].w);
            *(ushort4*)(ebf + (size_t)(base4 + j * 256) * 4) = o;
        }
    }
}

// ---------------- L2: t2 direct + alpha | conv_dedup ------------------------
// t2a blocks FIRST (long per-block GEMV) so they overlap conv (R13 lesson).
// bid [0,1024): t2[b,n] = tgt[b,:]@Wc[:,n] + bc[n]; ntile==0 emits alpha
// bid [1024,11024): per-node conv (one wave per node, skip unflagged)
__global__ __launch_bounds__(256) void k_stage2(
    const ushort* __restrict__ ebf, const int* __restrict__ adj_cols,
    const float* __restrict__ adj_vals, const int* __restrict__ flags,
    ushort* __restrict__ gbf,
    const float* __restrict__ tgt, const float* __restrict__ Wc,
    const float* __restrict__ bc, const float* __restrict__ v,
    const float* __restrict__ c0, float* __restrict__ t2,
    float* __restrict__ alpha)
{
    __shared__ float x_s[4 * TWO_D];
    int bid = blockIdx.x;
    int tid = threadIdx.x;
    int wv = tid >> 6, lane = tid & 63;

    if (bid < 1024) {
        int t = bid;
        int btile = t >> 2, ntile = t & 3;
        int b0 = btile * 4, n0 = ntile * 64;
        int j = wv;
        for (int i = tid; i < 4 * TWO_D; i += 256) x_s[i] = tgt[b0 * TWO_D + i];
        __syncthreads();

        float acc = bc[n0 + lane];
        const float* xr = x_s + j * TWO_D;
#pragma unroll 8
        for (int k = 0; k < TWO_D; ++k)
            acc += xr[k] * Wc[k * DD + n0 + lane];
        t2[(b0 + j) * DD + n0 + lane] = acc;

        if (ntile == 0) {
            float s = 0.f;
#pragma unroll
            for (int i = 0; i < 8; ++i) s += xr[lane + 64 * i] * v[lane + 64 * i];
            s = wave_sum64(s);
            if (lane == 0) {
                float a = 1.f + 1.f / (1.f + expf(-(s + c0[0])));
                if (a == 1.f) a = 1.00001f;
                alpha[b0 + j] = a;
            }
        }
    } else {
        int n = (bid - 1024) * 4 + wv;
        if (flags[n] != 1) return;
        int colv = 0; float valv = 0.f;
        if (lane < DEG) { colv = adj_cols[n * DEG + lane]; valv = adj_vals[n * DEG + lane]; }
        int cols[DEG]; float vals[DEG];
#pragma unroll
        for (int k = 0; k < DEG; ++k) {
            cols[k] = __shfl(colv, k, 64);
            vals[k] = __shfl(valv, k, 64);
        }
        ushort4 s = *(const ushort4*)(ebf + (size_t)n * DD + lane * 4);
        ushort4 e[DEG];
#pragma unroll
        for (int k = 0; k < DEG; ++k)
            e[k] = *(const ushort4*)(ebf + (size_t)cols[k] * DD + lane * 4);
        float a0 = bf2f(s.x), a1 = bf2f(s.y), a2 = bf2f(s.z), a3 = bf2f(s.w);
#pragma unroll
        for (int k = 0; k < DEG; ++k) {
            float vv = vals[k];
            a0 += vv * bf2f(e[k].x); a1 += vv * bf2f(e[k].y);
            a2 += vv * bf2f(e[k].z); a3 += vv * bf2f(e[k].w);
        }
        ushort4 o;
        o.x = f2bf(0.5f * a0); o.y = f2bf(0.5f * a1);
        o.z = f2bf(0.5f * a2); o.w = f2bf(0.5f * a3);
        *(ushort4*)(gbf + (size_t)n * DD + lane * 4) = o;
    }
}

// ---------------- L3 (MFMA, 128-row tile) -----------------------------------
__global__ __launch_bounds__(256, 2) void k_scores_mfma(
    const int* __restrict__ items, const ushort* __restrict__ gbf,
    const ushort* __restrict__ w1t, const float* __restrict__ t2,
    const float* __restrict__ at_w0, float* __restrict__ scores)
{
    __shared__ __align__(16) ushort sA[128 * 72];   // 18432 B
    __shared__ __align__(16) ushort sB[256 * 72];   // 36864 B
    __shared__ float sred[128][4];
    __shared__ int s_items[128];
    int tid = threadIdx.x;
    int blk = blockIdx.x;
    int lane = tid & 63, wv = tid >> 6;
    int cn = lane & 15, q = lane >> 4;
    int n0 = wv * 64;

    if (tid < 128) s_items[tid] = items[blk * 128 + tid];
    __syncthreads();

    floatx4 acc[8][4];
#pragma unroll
    for (int mt = 0; mt < 8; ++mt)
#pragma unroll
        for (int nt = 0; nt < 4; ++nt)
            acc[mt][nt] = (floatx4){0.f, 0.f, 0.f, 0.f};

#pragma unroll 1
    for (int kc = 0; kc < 4; ++kc) {
#pragma unroll
        for (int it = 0; it < 4; ++it) {
            int i = tid + it * 256;
            int row = i >> 3, seg = i & 7;
            *(uint4*)(sA + row * 72 + seg * 8) =
                *(const uint4*)(gbf + (size_t)s_items[row] * DD + kc * 64 + seg * 8);
        }
#pragma unroll
        for (int it = 0; it < 8; ++it) {
            int i = tid + it * 256;
            int n = i >> 3, seg = i & 7;
            *(uint4*)(sB + n * 72 + seg * 8) =
                *(const uint4*)(w1t + n * DD + kc * 64 + seg * 8);
        }
        __syncthreads();
#pragma unroll
        for (int ks = 0; ks < 2; ++ks) {
            short8 af[8], bfr[4];
#pragma unroll
            for (int mt = 0; mt < 8; ++mt)
                af[mt] = *(const short8*)(sA + (mt * 16 + cn) * 72 + ks * 32 + q * 8);
#pragma unroll
            for (int nt = 0; nt < 4; ++nt)
                bfr[nt] = *(const short8*)(sB + (n0 + nt * 16 + cn) * 72 + ks * 32 + q * 8);
#pragma unroll
            for (int mt = 0; mt < 8; ++mt)
#pragma unroll
                for (int nt = 0; nt < 4; ++nt)
                    acc[mt][nt] = __builtin_amdgcn_mfma_f32_16x16x32_bf16(
                        af[mt], bfr[nt], acc[mt][nt], 0, 0, 0);
        }
        __syncthreads();
    }

    float w0v[4];
#pragma unroll
    for (int nt = 0; nt < 4; ++nt) w0v[nt] = at_w0[n0 + nt * 16 + cn];
#pragma unroll
    for (int mt = 0; mt < 8; ++mt) {
#pragma unroll
        for (int r = 0; r < 4; ++r) {
            int row_in = q * 4 + r;
            int row = mt * 16 + row_in;
            int b = (blk * 128 + row) / LL;
            const float* t2b = t2 + b * DD;
            float p = 0.f;
#pragma unroll
            for (int nt = 0; nt < 4; ++nt) {
                int col = n0 + nt * 16 + cn;
                float vv = acc[mt][nt][r] + t2b[col];
                p += fmaxf(vv, 0.f) * w0v[nt];
            }
            p += __shfl_xor(p, 1, 64);
            p += __shfl_xor(p, 2, 64);
            p += __shfl_xor(p, 4, 64);
            p += __shfl_xor(p, 8, 64);
            if (cn == 0) sred[row][wv] = p;
        }
    }
    __syncthreads();
    if (tid < 128)
        scores[blk * 128 + tid] = sred[tid][0] + sred[tid][1] + sred[tid][2] + sred[tid][3];
}

__device__ __forceinline__ float pw(float z, float invv) {
    return hw_exp2(invv * hw_log2(z));   // z=0 -> exp2(-inf)=0, correct limit
}

// ---------------- L4: entmax + weighted sum + selu + L2 norm ----------------
__global__ __launch_bounds__(256) void k_entmax_out(
    const float* __restrict__ scores, const float* __restrict__ alpha,
    const int* __restrict__ items, const ushort* __restrict__ gbf,
    float* __restrict__ out)
{
    __shared__ float attn_s[LL];
    __shared__ int s_it[LL];
    __shared__ float red[4];
    int b = blockIdx.x;
    int tid = threadIdx.x;

    if (tid >= 192 && tid < 192 + LL) s_it[tid - 192] = items[b * LL + (tid - 192)];

    if (tid < 64) {
        int l = tid;
        float a = alpha[b];
        float am1 = a - 1.f;
        float invv = 1.f / am1;
        float x = (l < LL) ? scores[b * LL + l] : -__builtin_inff();
        float Xa = x * am1;

        float mx = wave_max64(Xa);
        float tau_lo = mx - 1.f;
        float tau_hi = mx - hw_exp2(am1 * hw_log2(1.f / (float)LL));

        float f_lo = wave_sum64(pw(fmaxf(Xa - tau_lo, 0.f), invv)) - 1.f;

        float dm = tau_hi - tau_lo;
        float tau_m = tau_lo;
#pragma unroll 1
        for (int it = 0; it < NITER; ++it) {
            dm *= 0.5f;
            tau_m = tau_lo + dm;
            // exact early-exit: once dm rounds away, every remaining
            // iteration is a no-op (rounding monotonicity) -> identical result
            if (tau_m == tau_lo) break;
            float f_m = wave_sum64(pw(fmaxf(Xa - tau_m, 0.f), invv)) - 1.f;
            if (f_m * f_lo >= 0.f) tau_lo = tau_m;
        }
        float pm = pw(fmaxf(Xa - tau_m, 0.f), invv);
        float s = wave_sum64(pm);
        if (l < LL) attn_s[l] = pm / s;
    }
    __syncthreads();

    int d = tid;
    float c = 0.f;
#pragma unroll
    for (int l = 0; l < LL; ++l)
        c += attn_s[l] * bf2f(gbf[(size_t)s_it[l] * DD + d]);

    const float SC = 1.0507009873554805f;
    const float AL = 1.6732632423543772f;
    c = SC * (c > 0.f ? c : AL * expm1f(c));

    float ss = wave_sum64(c * c);
    int wv = tid >> 6, lane = tid & 63;
    if (lane == 0) red[wv] = ss;
    __syncthreads();
    float tot = red[0] + red[1] + red[2] + red[3];
    out[b * DD + d] = c / sqrtf(tot);
}

extern "C" void kernel_launch(void* const* d_in, const int* in_sizes, int n_in,
                              void* d_out, int out_size, void* d_ws, size_t ws_size,
                              hipStream_t stream) {
    const int*   items     = (const int*)  d_in[0];
    const float* tgt       = (const float*)d_in[3];
    const float* item_emb  = (const float*)d_in[4];
    const int*   adj_cols  = (const int*)  d_in[6];
    const float* adj_vals  = (const float*)d_in[7];
    const float* wf_w      = (const float*)d_in[8];
    const float* wf_b      = (const float*)d_in[9];
    const float* alphaw_w  = (const float*)d_in[10];
    const float* alphaw_b  = (const float*)d_in[11];
    const float* at_w0     = (const float*)d_in[12];
    const float* at_w1     = (const float*)d_in[13];
    const float* at_w2     = (const float*)d_in[14];
    const float* at_bias   = (const float*)d_in[15];

    const size_t SZ_TAB = (size_t)NN * DD * sizeof(ushort);      // 20.48 MB
    char* ws = (char*)d_ws;
    ushort* gbf = (ushort*)ws;   ws += SZ_TAB;
    ushort* ebf = (ushort*)ws;   ws += SZ_TAB;
    ushort* w1t = (ushort*)ws;   ws += (size_t)DD * DD * sizeof(ushort);
    int*   flags = (int*)ws;     ws += (size_t)NN * sizeof(int);
    float* Wc     = (float*)ws;  ws += (size_t)TWO_D * DD * sizeof(float);
    float* bcv    = (float*)ws;  ws += (size_t)DD * sizeof(float);
    float* vv     = (float*)ws;  ws += (size_t)TWO_D * sizeof(float);
    float* c0v    = (float*)ws;  ws += 16 * sizeof(float);
    float* t2     = (float*)ws;  ws += (size_t)BB * DD * sizeof(float);
    float* alpha  = (float*)ws;  ws += ((size_t)BB + 32) * sizeof(float);
    float* scores = (float*)ws;  ws += (size_t)BB * LL * sizeof(float);
    float* out    = (float*)d_out;

    k_stage1<<<1962, 256, 0, stream>>>(item_emb, ebf, items, flags,
                                       wf_w, wf_b, at_w2, at_bias,
                                       alphaw_w, alphaw_b, at_w1,
                                       Wc, vv, bcv, c0v, w1t);
    k_stage2<<<11024, 256, 0, stream>>>(ebf, adj_cols, adj_vals, flags, gbf,
                                        tgt, Wc, bcv, vv, c0v, t2, alpha);
    k_scores_mfma<<<(BB * LL) / 128, 256, 0, stream>>>(items, gbf, w1t, t2, at_w0, scores);
    k_entmax_out<<<BB, 256, 0, stream>>>(scores, alpha, items, gbf, out);
}